// Round 1
// baseline (358.862 us; speedup 1.0000x reference)
//
#include <hip/hip_runtime.h>

#define BB 64
#define LL 512
#define TT 52
#define START_TAG 50
#define END_TAG 51

__device__ __forceinline__ unsigned umin32(unsigned a, unsigned b) { return a < b ? a : b; }

// Argmax over this wave's 13 sources vs the GLOBAL max bits Mb.
// Key byte = (bits!=Mb)<<6 | global_source_idx. Min over keys (within wave here,
// across the 4 wave-bytes at compaction) == smallest index achieving the max
// == jnp.argmax first-max-wins (fp ties share bits; +-0 maxima measure-zero).
// Template WB keeps bv[] indices compile-time constant (no scratch spill).
template<int WB>
__device__ __forceinline__ unsigned argmax13(const float (&bv)[TT], unsigned Mb) {
    unsigned kk[13];
    #pragma unroll
    for (int q = 0; q < 13; ++q) {
        unsigned e = __float_as_uint(bv[WB + q]) ^ Mb;
        kk[q] = (umin32(e, 1u) << 6) | (unsigned)(WB + q);
    }
    unsigned k0 = umin32(umin32(kk[0], kk[1]), kk[2]);
    unsigned k1 = umin32(umin32(kk[3], kk[4]), kk[5]);
    unsigned k2 = umin32(umin32(kk[6], kk[7]), kk[8]);
    unsigned k3 = umin32(umin32(kk[9], kk[10]), kk[11]);
    return umin32(umin32(umin32(k0, k1), umin32(k2, k3)), kk[12]);
}

// R9: barrier-free forward recurrence via full replication.
// Every wave computes the complete 52-source max each step (52 readlane +
// 104 add + ~26 max3), so P_t -> P_{t+1} never leaves registers and there is
// NO per-step barrier / LDS round trip (was ~70% of the 975 cy/step in R8).
// Backpointers: each wave writes a 1-byte partial-argmax key into a 64-step
// LDS window [row][tag][wave]; a per-chunk (64 steps) barrier + 4-byte-min
// compaction produces s_bp. 16 barriers total instead of 511.
// Exactness: (f + c[i]) + P[i] order identical to reference; max tree exact;
// replicated waves compute bit-identical bestP (same inputs, same op order).
__launch_bounds__(256, 1)
__global__ void viterbi_kernel(const float* __restrict__ feats,
                               const int* __restrict__ mask,
                               const float* __restrict__ trans,
                               int* __restrict__ out) {
    const int b    = blockIdx.x;
    const int tid  = threadIdx.x;
    const int lane = tid & 63;
    const int w    = tid >> 6;

    __shared__ unsigned int  s_bpw32[64 * TT];     // bp-key window: 4 bytes per (row,tag), 13312 B
    __shared__ unsigned char s_bp[LL * TT];        // final backpointers (26624 B)
    __shared__ int s_tags[LL];
    __shared__ unsigned char s_map[8 * 52];
    __shared__ int s_ent[8];

    // ---- length n = sum(mask[b,:]) ----
    int partial = 0;
    const int* mrow = mask + b * LL;
    #pragma unroll
    for (int k = 0; k < LL / 64; ++k) partial += mrow[lane + 64 * k];
    #pragma unroll
    for (int off = 32; off >= 1; off >>= 1) partial += __shfl_xor(partial, off, 64);
    const int n = partial;  // uniform, in [256, 512]

    const int flane = (lane < TT) ? lane : (TT - 1);   // clamped lane: always in-bounds loads
    const float* frow = feats + (size_t)b * LL * TT;

    // ---- full transition column per lane (replicated in every wave) ----
    float creg[TT];
    #pragma unroll
    for (int i = 0; i < TT; ++i) creg[i] = trans[i * TT + flane];
    const float tE = trans[flane * TT + END_TAG];

    // ---- P0 in-register ----
    float bestP = (lane < TT) ? (frow[lane] + trans[START_TAG * TT + lane]) : -3.0e38f;

    // ---- f prefetch pipeline, 2 steps deep (global direct; L1 absorbs 4x wave redundancy) ----
    float fA = frow[1 * TT + flane];   // f for t=1
    float fB = frow[2 * TT + flane];   // f for t=2

    #pragma unroll
    for (int k = 0; k < LL / 256; ++k) s_tags[tid + 256 * k] = 0;

    unsigned char* bpw = (unsigned char*)s_bpw32;
    const int myByte = (lane < TT) ? (lane * 4 + w) : 0;   // byte slot within window row

    // ---- forward: 64-step chunks; barrier only at chunk boundaries ----
    int t = 1;
    for (int c = 0; 64 * c < n; ++c) {
        int tend = 64 * (c + 1); if (tend > n) tend = n;
        for (; t < tend; ++t) {
            // prefetch f[t+2]
            int tp = t + 2; if (tp > LL - 1) tp = LL - 1;
            float fC = frow[tp * TT + flane];

            // bv[i] = (f[t][j] + trans[i][j]) + P[i]   -- exact reference order
            float bv[TT];
            #pragma unroll
            for (int i = 0; i < TT; ++i) {
                float Pi = __int_as_float(__builtin_amdgcn_readlane(__float_as_int(bestP), i));
                bv[i] = (fA + creg[i]) + Pi;
            }

            // 52-value max tree (max3-shaped; max is exactly associative/commutative)
            float l1[18];
            #pragma unroll
            for (int g = 0; g < 17; ++g)
                l1[g] = fmaxf(fmaxf(bv[3 * g], bv[3 * g + 1]), bv[3 * g + 2]);
            l1[17] = bv[51];
            float l2[6];
            #pragma unroll
            for (int g = 0; g < 6; ++g)
                l2[g] = fmaxf(fmaxf(l1[3 * g], l1[3 * g + 1]), l1[3 * g + 2]);
            float M = fmaxf(fmaxf(fmaxf(l2[0], l2[1]), fmaxf(l2[2], l2[3])),
                            fmaxf(l2[4], l2[5]));

            // per-wave partial argmax key (13 sources), vs global M
            unsigned Mb = __float_as_uint(M);
            unsigned km;
            if      (w == 0) km = argmax13<0 >(bv, Mb);
            else if (w == 1) km = argmax13<13>(bv, Mb);
            else if (w == 2) km = argmax13<26>(bv, Mb);
            else             km = argmax13<39>(bv, Mb);

            bestP = M;   // bit-identical across all 4 waves

            if (lane < TT)
                bpw[(t & 63) * (TT * 4) + myByte] = (unsigned char)km;  // byte-disjoint, race-free

            fA = fB; fB = fC;
        }
        // ---- compact window -> s_bp (min of 4 wave-keys, &63) ----
        __syncthreads();
        #pragma unroll
        for (int k = 0; k < 13; ++k) {
            int e = tid + 256 * k;                   // e = row*52 + j, covers 64*52 = 3328
            unsigned wv = s_bpw32[e];
            unsigned mm = umin32(umin32(wv & 255u, (wv >> 8) & 255u),
                                 umin32((wv >> 16) & 255u, wv >> 24)) & 63u;
            s_bp[c * 3328 + e] = (unsigned char)mm;  // == s_bp[(64c+row)*52 + j]
        }
        __syncthreads();
    }

    // ---- pointer0 = argmax_i ( P_{n-1}[i] + trans[i,END] ), min-index tie ----
    float lv = (lane < TT) ? (bestP + tE) : -3.0e38f;
    int li = lane;
    #pragma unroll
    for (int off = 32; off >= 1; off >>= 1) {
        float ov = __shfl_xor(lv, off, 64);
        int   oi = __shfl_xor(li, off, 64);
        if (ov > lv || (ov == lv && oi < li)) { lv = ov; li = oi; }
    }
    const int ptr0 = li;

    __syncthreads();

    // ---- backtrace: 8-chunk two-phase parallel pointer chase ----
    const int W  = n - 1;
    const int Sc = (W + 7) >> 3;
    {
        int v0 = tid;
        int k0 = v0 / 52, y0 = v0 - k0 * 52;
        int v1 = tid + 256;
        bool a1 = (v1 < 416);
        int k1 = a1 ? v1 / 52 : 7, y1 = a1 ? (v1 - k1 * 52) : 0;
        int s0a = k0 * Sc, s1a = min(s0a + Sc, W);
        int s0b = k1 * Sc, s1b = min(s0b + Sc, W);
        int xa = y0, xb = y1;
        for (int s = 0; s < Sc; ++s) {
            int ga = s0a + s, gb = s0b + s;
            if (ga < s1a) xa = s_bp[(n - 1 - ga) * TT + xa];
            if (gb < s1b) xb = s_bp[(n - 1 - gb) * TT + xb];
        }
        s_map[k0 * 52 + y0] = (unsigned char)xa;
        if (a1) s_map[k1 * 52 + y1] = (unsigned char)xb;
    }
    __syncthreads();
    if (tid == 0) {
        int e = ptr0; s_ent[0] = e;
        #pragma unroll
        for (int k = 1; k < 8; ++k) { e = s_map[(k - 1) * 52 + e]; s_ent[k] = e; }
        s_tags[n - 1] = ptr0;
        s_tags[LL - 1] = ptr0;   // reference quirk: decode[L-1] = pointer0 always
    }
    __syncthreads();
    if (tid < 8) {
        int k = tid;
        int x = s_ent[k];
        int ss0 = k * Sc, ss1 = min(ss0 + Sc, W);
        for (int s = ss0; s < ss1; ++s) {
            x = s_bp[(n - 1 - s) * TT + x];
            s_tags[n - 2 - s] = x;
        }
    }
    __syncthreads();

    // ---- coalesced output write ----
    int* orow = out + b * LL;
    #pragma unroll
    for (int k = 0; k < LL / 256; ++k) orow[tid + 256 * k] = s_tags[tid + 256 * k];
}

extern "C" void kernel_launch(void* const* d_in, const int* in_sizes, int n_in,
                              void* d_out, int out_size, void* d_ws, size_t ws_size,
                              hipStream_t stream) {
    const float* feats = (const float*)d_in[0];
    const int*   mask  = (const int*)d_in[1];
    const float* trans = (const float*)d_in[2];
    int* out = (int*)d_out;
    viterbi_kernel<<<dim3(BB), dim3(256), 0, stream>>>(feats, mask, trans, out);
}